// Round 1
// baseline (82.970 us; speedup 1.0000x reference)
//
#include <hip/hip_runtime.h>
#include <math.h>

#define FS 8
#define CC 3
#define HH 720
#define WW 1280
#define HW (HH * WW)

// 16B vector with 4B alignment -> compiler emits global_load_dwordx4
// (gfx950 supports dword-aligned wide loads)
typedef float f4 __attribute__((ext_vector_type(4), aligned(4)));

// cos(pi*k/8), sin(pi*k/8), (-1)^k for k = -3..4 (index j = k+3)
__constant__ float COSK[8] = {0.38268343f, 0.70710678f, 0.92387953f, 1.0f,
                              0.92387953f, 0.70710678f, 0.38268343f, 0.0f};
__constant__ float SINK[8] = {-0.92387953f, -0.70710678f, -0.38268343f, 0.0f,
                              0.38268343f, 0.70710678f, 0.92387953f, 1.0f};
__constant__ float SGNK[8] = {-1.0f, 1.0f, -1.0f, 1.0f, -1.0f, 1.0f, -1.0f, 1.0f};

__device__ __forceinline__ void sinc_weights(float s, float* wgt) {
    const float PI = 3.14159265358979f;
    float sp = __sinf(PI * s);          // sin(pi*s)
    float s8, c8;
    __sincosf(PI * s * 0.125f, &s8, &c8);  // sin/cos(pi*s/8)
#pragma unroll
    for (int j = 0; j < 8; ++j) {
        float t = s - (float)(j - 3);
        float win = c8 * COSK[j] + s8 * SINK[j];      // cos(pi*t/8)
        // sinc(t) = (-1)^k * sin(pi*s) / (pi*t); only k=0 can have t==0
        float r = (t == 0.0f) ? 1.0f : __fdividef(sp * SGNK[j], PI * t);
        wgt[j] = win * r;
    }
}

__global__ __launch_bounds__(256) void warp_kernel(const float* __restrict__ x,
                                                   const float* __restrict__ flow,
                                                   float* __restrict__ out) {
    int idx = blockIdx.x * blockDim.x + threadIdx.x;
    if (idx >= HW) return;
    int w = idx % WW;
    int h = idx / WW;

    float fx = flow[idx];        // flow[0,0,h,w]
    float fy = flow[HW + idx];   // flow[0,1,h,w]

    float rfx = floorf(fx);
    float rfy = floorf(fy);
    float sx = fx - rfx;
    float sy = fy - rfy;
    int bx = w + (int)rfx;
    int by = h + (int)rfy;

    float cxw[8], cyw[8];
    sinc_weights(sx, cxw);
    sinc_weights(sy, cyw);

    // clipped row offsets (shared across channels)
    int yoff[8];
#pragma unroll
    for (int i = 0; i < 8; ++i) {
        int yy = by + (i - 3);
        yy = min(max(yy, 0), HH - 1);
        yoff[i] = yy * WW;
    }

    float res0 = 0.f, res1 = 0.f, res2 = 0.f;
    bool fastx = (bx >= 3) && (bx <= WW - 5);  // columns bx-3..bx+4 all interior

    if (fastx) {
        const float* xc0 = x + (bx - 3);
        const float* xc1 = xc0 + HW;
        const float* xc2 = xc1 + HW;
#pragma unroll
        for (int i = 0; i < 8; ++i) {
            int o = yoff[i];
            float cyi = cyw[i];
            {
                f4 a = *(const f4*)(xc0 + o);
                f4 b = *(const f4*)(xc0 + o + 4);
                float rs = a.x * cxw[0] + a.y * cxw[1] + a.z * cxw[2] + a.w * cxw[3] +
                           b.x * cxw[4] + b.y * cxw[5] + b.z * cxw[6] + b.w * cxw[7];
                res0 = fmaf(cyi, rs, res0);
            }
            {
                f4 a = *(const f4*)(xc1 + o);
                f4 b = *(const f4*)(xc1 + o + 4);
                float rs = a.x * cxw[0] + a.y * cxw[1] + a.z * cxw[2] + a.w * cxw[3] +
                           b.x * cxw[4] + b.y * cxw[5] + b.z * cxw[6] + b.w * cxw[7];
                res1 = fmaf(cyi, rs, res1);
            }
            {
                f4 a = *(const f4*)(xc2 + o);
                f4 b = *(const f4*)(xc2 + o + 4);
                float rs = a.x * cxw[0] + a.y * cxw[1] + a.z * cxw[2] + a.w * cxw[3] +
                           b.x * cxw[4] + b.y * cxw[5] + b.z * cxw[6] + b.w * cxw[7];
                res2 = fmaf(cyi, rs, res2);
            }
        }
    } else {
        int xcl[8];
#pragma unroll
        for (int j = 0; j < 8; ++j) {
            int xx = bx + (j - 3);
            xcl[j] = min(max(xx, 0), WW - 1);
        }
#pragma unroll
        for (int i = 0; i < 8; ++i) {
            int o = yoff[i];
            float cyi = cyw[i];
            const float* p0 = x + o;
            const float* p1 = p0 + HW;
            const float* p2 = p1 + HW;
            float rs0 = 0.f, rs1 = 0.f, rs2 = 0.f;
#pragma unroll
            for (int j = 0; j < 8; ++j) {
                float cj = cxw[j];
                rs0 = fmaf(p0[xcl[j]], cj, rs0);
                rs1 = fmaf(p1[xcl[j]], cj, rs1);
                rs2 = fmaf(p2[xcl[j]], cj, rs2);
            }
            res0 = fmaf(cyi, rs0, res0);
            res1 = fmaf(cyi, rs1, res1);
            res2 = fmaf(cyi, rs2, res2);
        }
    }

    out[idx] = res0;
    out[HW + idx] = res1;
    out[2 * HW + idx] = res2;
}

extern "C" void kernel_launch(void* const* d_in, const int* in_sizes, int n_in,
                              void* d_out, int out_size, void* d_ws, size_t ws_size,
                              hipStream_t stream) {
    const float* x = (const float*)d_in[0];
    const float* flow = (const float*)d_in[1];
    float* out = (float*)d_out;
    int nthreads = HW;
    int block = 256;
    int grid = (nthreads + block - 1) / block;
    warp_kernel<<<grid, block, 0, stream>>>(x, flow, out);
}

// Round 2
// 71.409 us; speedup vs baseline: 1.1619x; 1.1619x over previous
//
#include <hip/hip_runtime.h>
#include <math.h>

#define FS 8
#define CC 3
#define HH 720
#define WW 1280
#define HW (HH * WW)

// 2D tiling: 64 wide x 4 tall per block (256 threads)
#define TW 64
#define TH 4
#define GX (WW / TW)   // 20
#define GY (HH / TH)   // 180
#define NWG (GX * GY)  // 3600 (divisible by 8 -> clean XCD swizzle)

// 16B vector with 4B alignment -> compiler emits global_load_dwordx4
typedef float f4 __attribute__((ext_vector_type(4), aligned(4)));

// cos(pi*k/8), sin(pi*k/8), (-1)^k for k = -3..4 (index j = k+3)
__constant__ float COSK[8] = {0.38268343f, 0.70710678f, 0.92387953f, 1.0f,
                              0.92387953f, 0.70710678f, 0.38268343f, 0.0f};
__constant__ float SINK[8] = {-0.92387953f, -0.70710678f, -0.38268343f, 0.0f,
                              0.38268343f, 0.70710678f, 0.92387953f, 1.0f};
__constant__ float SGNK[8] = {-1.0f, 1.0f, -1.0f, 1.0f, -1.0f, 1.0f, -1.0f, 1.0f};

__device__ __forceinline__ void sinc_weights(float s, float* wgt) {
    const float PI = 3.14159265358979f;
    float sp = __sinf(PI * s);             // sin(pi*s)
    float s8, c8;
    __sincosf(PI * s * 0.125f, &s8, &c8);  // sin/cos(pi*s/8)
#pragma unroll
    for (int j = 0; j < 8; ++j) {
        float t = s - (float)(j - 3);
        float win = c8 * COSK[j] + s8 * SINK[j];  // cos(pi*t/8)
        float r = (t == 0.0f) ? 1.0f : __fdividef(sp * SGNK[j], PI * t);
        wgt[j] = win * r;
    }
}

__global__ __launch_bounds__(256) void warp_kernel(const float* __restrict__ x,
                                                   const float* __restrict__ flow,
                                                   float* __restrict__ out) {
    // bijective XCD band swizzle: each XCD gets a contiguous band of tiles
    int bid = blockIdx.x;
    int swz = (bid & 7) * (NWG / 8) + (bid >> 3);
    int tx = swz % GX;
    int ty = swz / GX;
    int w = tx * TW + (threadIdx.x & 63);
    int h = ty * TH + (threadIdx.x >> 6);
    int idx = h * WW + w;

    float fx = flow[idx];        // flow[0,0,h,w]
    float fy = flow[HW + idx];   // flow[0,1,h,w]

    float rfx = floorf(fx);
    float rfy = floorf(fy);
    float sx = fx - rfx;
    float sy = fy - rfy;
    int bx = w + (int)rfx;
    int by = h + (int)rfy;

    float cxw[8], cyw[8];
    sinc_weights(sx, cxw);
    sinc_weights(sy, cyw);

    // clipped row offsets (shared across channels)
    int yoff[8];
#pragma unroll
    for (int i = 0; i < 8; ++i) {
        int yy = by + (i - 3);
        yy = min(max(yy, 0), HH - 1);
        yoff[i] = yy * WW;
    }

    float res0 = 0.f, res1 = 0.f, res2 = 0.f;
    bool fastx = (bx >= 3) && (bx <= WW - 5);  // columns bx-3..bx+4 all interior

    if (fastx) {
        const float* xc0 = x + (bx - 3);
        const float* xc1 = xc0 + HW;
        const float* xc2 = xc1 + HW;
#pragma unroll
        for (int i = 0; i < 8; ++i) {
            int o = yoff[i];
            float cyi = cyw[i];
            {
                f4 a = *(const f4*)(xc0 + o);
                f4 b = *(const f4*)(xc0 + o + 4);
                float rs = a.x * cxw[0] + a.y * cxw[1] + a.z * cxw[2] + a.w * cxw[3] +
                           b.x * cxw[4] + b.y * cxw[5] + b.z * cxw[6] + b.w * cxw[7];
                res0 = fmaf(cyi, rs, res0);
            }
            {
                f4 a = *(const f4*)(xc1 + o);
                f4 b = *(const f4*)(xc1 + o + 4);
                float rs = a.x * cxw[0] + a.y * cxw[1] + a.z * cxw[2] + a.w * cxw[3] +
                           b.x * cxw[4] + b.y * cxw[5] + b.z * cxw[6] + b.w * cxw[7];
                res1 = fmaf(cyi, rs, res1);
            }
            {
                f4 a = *(const f4*)(xc2 + o);
                f4 b = *(const f4*)(xc2 + o + 4);
                float rs = a.x * cxw[0] + a.y * cxw[1] + a.z * cxw[2] + a.w * cxw[3] +
                           b.x * cxw[4] + b.y * cxw[5] + b.z * cxw[6] + b.w * cxw[7];
                res2 = fmaf(cyi, rs, res2);
            }
        }
    } else {
        int xcl[8];
#pragma unroll
        for (int j = 0; j < 8; ++j) {
            int xx = bx + (j - 3);
            xcl[j] = min(max(xx, 0), WW - 1);
        }
#pragma unroll
        for (int i = 0; i < 8; ++i) {
            int o = yoff[i];
            float cyi = cyw[i];
            const float* p0 = x + o;
            const float* p1 = p0 + HW;
            const float* p2 = p1 + HW;
            float rs0 = 0.f, rs1 = 0.f, rs2 = 0.f;
#pragma unroll
            for (int j = 0; j < 8; ++j) {
                float cj = cxw[j];
                rs0 = fmaf(p0[xcl[j]], cj, rs0);
                rs1 = fmaf(p1[xcl[j]], cj, rs1);
                rs2 = fmaf(p2[xcl[j]], cj, rs2);
            }
            res0 = fmaf(cyi, rs0, res0);
            res1 = fmaf(cyi, rs1, res1);
            res2 = fmaf(cyi, rs2, res2);
        }
    }

    out[idx] = res0;
    out[HW + idx] = res1;
    out[2 * HW + idx] = res2;
}

extern "C" void kernel_launch(void* const* d_in, const int* in_sizes, int n_in,
                              void* d_out, int out_size, void* d_ws, size_t ws_size,
                              hipStream_t stream) {
    const float* x = (const float*)d_in[0];
    const float* flow = (const float*)d_in[1];
    float* out = (float*)d_out;
    warp_kernel<<<NWG, 256, 0, stream>>>(x, flow, out);
}

// Round 3
// 60.043 us; speedup vs baseline: 1.3819x; 1.1893x over previous
//
#include <hip/hip_runtime.h>
#include <math.h>

#define FS 8
#define CC 3
#define HH 720
#define WW 1280
#define HW (HH * WW)

// 2D tiling: 64 wide x 4 tall per block (256 threads)
#define TW 64
#define TH 4
#define GX (WW / TW)   // 20
#define GY (HH / TH)   // 180
#define NWG (GX * GY)  // 3600 (divisible by 8 -> clean XCD swizzle)

// fp16 workspace layout: copy A at even base, copy B at odd base (+1),
// so any 8-tap window can be read as ONE 4B-aligned dwordx4.
#define SW 1288                 // fp16 row stride (even, >= 1280+8)
#define PLANE (HH * SW)         // per-channel fp16 plane
#define WS_HALFS (6 * PLANE + 8)
#define WS_BYTES ((size_t)WS_HALFS * 2)

typedef float f4 __attribute__((ext_vector_type(4), aligned(4)));
typedef _Float16 h8 __attribute__((ext_vector_type(8), aligned(4)));

// cos(pi*k/8), sin(pi*k/8), (-1)^k for k = -3..4 (index j = k+3)
__constant__ float COSK[8] = {0.38268343f, 0.70710678f, 0.92387953f, 1.0f,
                              0.92387953f, 0.70710678f, 0.38268343f, 0.0f};
__constant__ float SINK[8] = {-0.92387953f, -0.70710678f, -0.38268343f, 0.0f,
                              0.38268343f, 0.70710678f, 0.92387953f, 1.0f};
__constant__ float SGNK[8] = {-1.0f, 1.0f, -1.0f, 1.0f, -1.0f, 1.0f, -1.0f, 1.0f};

__device__ __forceinline__ void sinc_weights(float s, float* wgt) {
    const float PI = 3.14159265358979f;
    float sp = __sinf(PI * s);             // sin(pi*s)
    float s8, c8;
    __sincosf(PI * s * 0.125f, &s8, &c8);  // sin/cos(pi*s/8)
#pragma unroll
    for (int j = 0; j < 8; ++j) {
        float t = s - (float)(j - 3);
        float win = c8 * COSK[j] + s8 * SINK[j];  // cos(pi*t/8)
        float r = (t == 0.0f) ? 1.0f : __fdividef(sp * SGNK[j], PI * t);
        wgt[j] = win * r;
    }
}

// x (f32 CHW) -> two fp16 copies in ws (even-base and odd-base)
__global__ __launch_bounds__(256) void conv_kernel(const float* __restrict__ x,
                                                   _Float16* __restrict__ ws) {
    int tid = blockIdx.x * blockDim.x + threadIdx.x;  // 3*720*320 threads
    if (tid >= CC * HH * (WW / 4)) return;
    int k4 = tid % (WW / 4);
    int rest = tid / (WW / 4);       // c*HH + h
    int k = k4 * 4;
    f4 v = *(const f4*)(x + rest * WW + k);
    int dst = rest * SW + k;
    _Float16 a = (_Float16)v.x, b = (_Float16)v.y,
             c = (_Float16)v.z, d = (_Float16)v.w;
    // copy A: 8B aligned store
    typedef _Float16 h4 __attribute__((ext_vector_type(4), aligned(8)));
    *(h4*)(ws + dst) = (h4){a, b, c, d};
    // copy B at odd base: scalar stores
    _Float16* wb = ws + 3 * PLANE + 1 + dst;
    wb[0] = a; wb[1] = b; wb[2] = c; wb[3] = d;
}

__global__ __launch_bounds__(256) void warp_kernel(const float* __restrict__ x,
                                                   const float* __restrict__ flow,
                                                   const _Float16* __restrict__ hx,
                                                   float* __restrict__ out) {
    // bijective XCD band swizzle
    int bid = blockIdx.x;
    int swz = (bid & 7) * (NWG / 8) + (bid >> 3);
    int tx = swz % GX;
    int ty = swz / GX;
    int w = tx * TW + (threadIdx.x & 63);
    int h = ty * TH + (threadIdx.x >> 6);
    int idx = h * WW + w;

    float fx = flow[idx];
    float fy = flow[HW + idx];

    float rfx = floorf(fx);
    float rfy = floorf(fy);
    float sx = fx - rfx;
    float sy = fy - rfy;
    int bx = w + (int)rfx;
    int by = h + (int)rfy;

    float cxw[8], cyw[8];
    sinc_weights(sx, cxw);
    sinc_weights(sy, cyw);

    float res0 = 0.f, res1 = 0.f, res2 = 0.f;
    bool fastx = (bx >= 3) && (bx <= WW - 5);

    if (fastx) {
        int s = bx - 3;
        // clipped row offsets in fp16-plane units
        int yoff[8];
#pragma unroll
        for (int i = 0; i < 8; ++i) {
            int yy = by + (i - 3);
            yy = min(max(yy, 0), HH - 1);
            yoff[i] = yy * SW;
        }
        const _Float16* hp = hx + ((s & 1) ? (3 * PLANE + 1) : 0) + s;
#pragma unroll
        for (int i = 0; i < 8; ++i) {
            int o = yoff[i];
            float cyi = cyw[i];
            {
                h8 v = *(const h8*)(hp + o);
                float rs = (float)v[0] * cxw[0] + (float)v[1] * cxw[1] +
                           (float)v[2] * cxw[2] + (float)v[3] * cxw[3] +
                           (float)v[4] * cxw[4] + (float)v[5] * cxw[5] +
                           (float)v[6] * cxw[6] + (float)v[7] * cxw[7];
                res0 = fmaf(cyi, rs, res0);
            }
            {
                h8 v = *(const h8*)(hp + o + PLANE);
                float rs = (float)v[0] * cxw[0] + (float)v[1] * cxw[1] +
                           (float)v[2] * cxw[2] + (float)v[3] * cxw[3] +
                           (float)v[4] * cxw[4] + (float)v[5] * cxw[5] +
                           (float)v[6] * cxw[6] + (float)v[7] * cxw[7];
                res1 = fmaf(cyi, rs, res1);
            }
            {
                h8 v = *(const h8*)(hp + o + 2 * PLANE);
                float rs = (float)v[0] * cxw[0] + (float)v[1] * cxw[1] +
                           (float)v[2] * cxw[2] + (float)v[3] * cxw[3] +
                           (float)v[4] * cxw[4] + (float)v[5] * cxw[5] +
                           (float)v[6] * cxw[6] + (float)v[7] * cxw[7];
                res2 = fmaf(cyi, rs, res2);
            }
        }
    } else {
        // exact f32 border path
        int yoff[8];
#pragma unroll
        for (int i = 0; i < 8; ++i) {
            int yy = by + (i - 3);
            yy = min(max(yy, 0), HH - 1);
            yoff[i] = yy * WW;
        }
        int xcl[8];
#pragma unroll
        for (int j = 0; j < 8; ++j) {
            int xx = bx + (j - 3);
            xcl[j] = min(max(xx, 0), WW - 1);
        }
#pragma unroll
        for (int i = 0; i < 8; ++i) {
            int o = yoff[i];
            float cyi = cyw[i];
            const float* p0 = x + o;
            const float* p1 = p0 + HW;
            const float* p2 = p1 + HW;
            float rs0 = 0.f, rs1 = 0.f, rs2 = 0.f;
#pragma unroll
            for (int j = 0; j < 8; ++j) {
                float cj = cxw[j];
                rs0 = fmaf(p0[xcl[j]], cj, rs0);
                rs1 = fmaf(p1[xcl[j]], cj, rs1);
                rs2 = fmaf(p2[xcl[j]], cj, rs2);
            }
            res0 = fmaf(cyi, rs0, res0);
            res1 = fmaf(cyi, rs1, res1);
            res2 = fmaf(cyi, rs2, res2);
        }
    }

    out[idx] = res0;
    out[HW + idx] = res1;
    out[2 * HW + idx] = res2;
}

// fallback (f32 gathers only) if workspace is too small
__global__ __launch_bounds__(256) void warp_kernel_f32(const float* __restrict__ x,
                                                       const float* __restrict__ flow,
                                                       float* __restrict__ out) {
    int bid = blockIdx.x;
    int swz = (bid & 7) * (NWG / 8) + (bid >> 3);
    int tx = swz % GX;
    int ty = swz / GX;
    int w = tx * TW + (threadIdx.x & 63);
    int h = ty * TH + (threadIdx.x >> 6);
    int idx = h * WW + w;

    float fx = flow[idx];
    float fy = flow[HW + idx];
    float rfx = floorf(fx);
    float rfy = floorf(fy);
    float sx = fx - rfx;
    float sy = fy - rfy;
    int bx = w + (int)rfx;
    int by = h + (int)rfy;

    float cxw[8], cyw[8];
    sinc_weights(sx, cxw);
    sinc_weights(sy, cyw);

    int yoff[8];
#pragma unroll
    for (int i = 0; i < 8; ++i) {
        int yy = by + (i - 3);
        yy = min(max(yy, 0), HH - 1);
        yoff[i] = yy * WW;
    }
    int xcl[8];
#pragma unroll
    for (int j = 0; j < 8; ++j) {
        int xx = bx + (j - 3);
        xcl[j] = min(max(xx, 0), WW - 1);
    }
    float res0 = 0.f, res1 = 0.f, res2 = 0.f;
#pragma unroll
    for (int i = 0; i < 8; ++i) {
        int o = yoff[i];
        float cyi = cyw[i];
        const float* p0 = x + o;
        const float* p1 = p0 + HW;
        const float* p2 = p1 + HW;
        float rs0 = 0.f, rs1 = 0.f, rs2 = 0.f;
#pragma unroll
        for (int j = 0; j < 8; ++j) {
            float cj = cxw[j];
            rs0 = fmaf(p0[xcl[j]], cj, rs0);
            rs1 = fmaf(p1[xcl[j]], cj, rs1);
            rs2 = fmaf(p2[xcl[j]], cj, rs2);
        }
        res0 = fmaf(cyi, rs0, res0);
        res1 = fmaf(cyi, rs1, res1);
        res2 = fmaf(cyi, rs2, res2);
    }
    out[idx] = res0;
    out[HW + idx] = res1;
    out[2 * HW + idx] = res2;
}

extern "C" void kernel_launch(void* const* d_in, const int* in_sizes, int n_in,
                              void* d_out, int out_size, void* d_ws, size_t ws_size,
                              hipStream_t stream) {
    const float* x = (const float*)d_in[0];
    const float* flow = (const float*)d_in[1];
    float* out = (float*)d_out;

    if (ws_size >= WS_BYTES) {
        _Float16* ws = (_Float16*)d_ws;
        int nconv = CC * HH * (WW / 4);
        conv_kernel<<<(nconv + 255) / 256, 256, 0, stream>>>(x, ws);
        warp_kernel<<<NWG, 256, 0, stream>>>(x, flow, ws, out);
    } else {
        warp_kernel_f32<<<NWG, 256, 0, stream>>>(x, flow, out);
    }
}